// Round 1
// baseline (2439.463 us; speedup 1.0000x reference)
//
#include <hip/hip_runtime.h>
#include <stdint.h>

// Problem constants
#define N_TOK 4096
#define DIM   1024
#define HFRAC 2048
#define HSW   4096
#define NEXP  8
#define NFRAC 4

typedef unsigned short u16;
typedef __bf16 bf16x8 __attribute__((ext_vector_type(8)));
typedef float  floatx4 __attribute__((ext_vector_type(4)));

struct alignas(8) us4 { u16 x, y, z, w; };

__device__ __forceinline__ u16 f32_to_bf16_raw(float f) {
    union { float f; uint32_t u; } v; v.f = f;
    uint32_t u = v.u;
    uint32_t r = 0x7FFFu + ((u >> 16) & 1u);   // round-to-nearest-even
    return (u16)((u + r) >> 16);
}
__device__ __forceinline__ float bf16_raw_to_f32(u16 h) {
    union { uint32_t u; float f; } v; v.u = ((uint32_t)h) << 16;
    return v.f;
}

// ---------------------------------------------------------------- cvt x -> bf16
__global__ __launch_bounds__(256) void cvt_bf16_kernel(
    const float* __restrict__ in, u16* __restrict__ out) {
    int i = blockIdx.x * 256 + threadIdx.x;   // group of 4 elems
    float4 v = reinterpret_cast<const float4*>(in)[i];
    us4 o = { f32_to_bf16_raw(v.x), f32_to_bf16_raw(v.y),
              f32_to_bf16_raw(v.z), f32_to_bf16_raw(v.w) };
    reinterpret_cast<us4*>(out)[i] = o;
}

// ---------------------------------------------------------------- router (fp32)
// one wave per token: logits[8] = x . router_w[e], softmax, top-2, renorm
__global__ __launch_bounds__(256) void router_kernel(
    const float* __restrict__ x, const float* __restrict__ rw,
    float* __restrict__ combine) {
    const int token = blockIdx.x * 4 + (threadIdx.x >> 6);
    const int lane  = threadIdx.x & 63;
    const float* xr = x + (size_t)token * DIM;

    float acc[NEXP];
#pragma unroll
    for (int e = 0; e < NEXP; ++e) acc[e] = 0.0f;
#pragma unroll
    for (int i = 0; i < DIM / 64; ++i) {
        int k = lane + i * 64;
        float xv = xr[k];
#pragma unroll
        for (int e = 0; e < NEXP; ++e) acc[e] += xv * rw[e * DIM + k];
    }
#pragma unroll
    for (int e = 0; e < NEXP; ++e) {
#pragma unroll
        for (int off = 32; off > 0; off >>= 1) acc[e] += __shfl_down(acc[e], off);
    }
    if (lane == 0) {
        float mx = acc[0];
#pragma unroll
        for (int e = 1; e < NEXP; ++e) mx = fmaxf(mx, acc[e]);
        float w[NEXP]; float s = 0.0f;
#pragma unroll
        for (int e = 0; e < NEXP; ++e) { w[e] = expf(acc[e] - mx); s += w[e]; }
        float inv = 1.0f / s;
#pragma unroll
        for (int e = 0; e < NEXP; ++e) w[e] *= inv;
        // top-2, lowest-index tie-break (strict >)
        int i1 = 0;
#pragma unroll
        for (int e = 1; e < NEXP; ++e) if (w[e] > w[i1]) i1 = e;
        int i2 = (i1 == 0) ? 1 : 0;
#pragma unroll
        for (int e = 0; e < NEXP; ++e) if (e != i1 && w[e] > w[i2]) i2 = e;
        float denom = fmaxf(w[i1] + w[i2], 1e-9f);
        float c1 = w[i1] / denom, c2 = w[i2] / denom;
        float* cr = combine + (size_t)token * NEXP;
#pragma unroll
        for (int e = 0; e < NEXP; ++e) cr[e] = 0.0f;
        cr[i1] = c1; cr[i2] = c2;
    }
}

// ---------------------------------------------------------------- rmsnorm -> bf16
__global__ __launch_bounds__(256) void rmsnorm_kernel(
    const float* __restrict__ x, const float* __restrict__ w,
    u16* __restrict__ xn) {
    const int row = blockIdx.x;
    const int tid = threadIdx.x;
    float4 v = reinterpret_cast<const float4*>(x + (size_t)row * DIM)[tid];
    float ss = v.x * v.x + v.y * v.y + v.z * v.z + v.w * v.w;
#pragma unroll
    for (int off = 32; off > 0; off >>= 1) ss += __shfl_down(ss, off);
    __shared__ float red[4];
    if ((tid & 63) == 0) red[tid >> 6] = ss;
    __syncthreads();
    float tot = red[0] + red[1] + red[2] + red[3];
    float scale = rsqrtf(tot * (1.0f / DIM) + 1e-6f);
    float4 wv = reinterpret_cast<const float4*>(w)[tid];
    us4 o = { f32_to_bf16_raw(v.x * scale * wv.x),
              f32_to_bf16_raw(v.y * scale * wv.y),
              f32_to_bf16_raw(v.z * scale * wv.z),
              f32_to_bf16_raw(v.w * scale * wv.w) };
    reinterpret_cast<us4*>(xn + (size_t)row * DIM)[tid] = o;
}

// ---------------------------------------------------------------- GEMM params
#define BM 128
#define BN 64
#define BK 64
#define LDK 72   // padded LDS row stride (elems) to break bank conflicts

// gemm1: h1 = A @ W1^T, h3 = A @ W3^T, G = bf16(silu(h1) * h3)
// A: [4096 x K] bf16 row-major.  W1/W3: [N x K] fp32 row-major.  G: [4096 x N] bf16.
__global__ __launch_bounds__(256) void gemm1_dual_kernel(
    const u16* __restrict__ A, const float* __restrict__ B1,
    const float* __restrict__ B3, u16* __restrict__ G,
    int N, int K) {
    __shared__ alignas(16) u16 sA[BM * LDK];
    __shared__ alignas(16) u16 sB1[BN * LDK];
    __shared__ alignas(16) u16 sB3[BN * LDK];

    const int tid  = threadIdx.x;
    const int wave = tid >> 6;
    const int lane = tid & 63;
    const int m0 = blockIdx.y * BM;
    const int n0 = blockIdx.x * BN;

    floatx4 acc1[2][4], acc3[2][4];
    floatx4 zero = { 0.f, 0.f, 0.f, 0.f };
#pragma unroll
    for (int mt = 0; mt < 2; ++mt)
#pragma unroll
        for (int nt = 0; nt < 4; ++nt) { acc1[mt][nt] = zero; acc3[mt][nt] = zero; }

    for (int k0 = 0; k0 < K; k0 += BK) {
        // stage A (bf16, 16B loads): 128x64 elems
#pragma unroll
        for (int it = 0; it < 4; ++it) {
            int idx = it * 2048 + tid * 8;
            int r = idx >> 6, c = idx & 63;
            int4 v = *reinterpret_cast<const int4*>(A + (size_t)(m0 + r) * K + k0 + c);
            *reinterpret_cast<int4*>(&sA[r * LDK + c]) = v;
        }
        // stage B1,B3 (fp32 -> bf16): 64x64 elems each
#pragma unroll
        for (int it = 0; it < 4; ++it) {
            int idx = it * 1024 + tid * 4;
            int r = idx >> 6, c = idx & 63;
            size_t goff = (size_t)(n0 + r) * K + k0 + c;
            float4 v1 = *reinterpret_cast<const float4*>(B1 + goff);
            float4 v3 = *reinterpret_cast<const float4*>(B3 + goff);
            us4 o1 = { f32_to_bf16_raw(v1.x), f32_to_bf16_raw(v1.y),
                       f32_to_bf16_raw(v1.z), f32_to_bf16_raw(v1.w) };
            us4 o3 = { f32_to_bf16_raw(v3.x), f32_to_bf16_raw(v3.y),
                       f32_to_bf16_raw(v3.z), f32_to_bf16_raw(v3.w) };
            *reinterpret_cast<us4*>(&sB1[r * LDK + c]) = o1;
            *reinterpret_cast<us4*>(&sB3[r * LDK + c]) = o3;
        }
        __syncthreads();
#pragma unroll
        for (int ks = 0; ks < 2; ++ks) {
            const int kk = ks * 32 + (lane >> 4) * 8;
            bf16x8 af[2], b1f[4], b3f[4];
#pragma unroll
            for (int mt = 0; mt < 2; ++mt)
                af[mt] = *reinterpret_cast<const bf16x8*>(
                    &sA[(wave * 32 + mt * 16 + (lane & 15)) * LDK + kk]);
#pragma unroll
            for (int nt = 0; nt < 4; ++nt) {
                b1f[nt] = *reinterpret_cast<const bf16x8*>(
                    &sB1[(nt * 16 + (lane & 15)) * LDK + kk]);
                b3f[nt] = *reinterpret_cast<const bf16x8*>(
                    &sB3[(nt * 16 + (lane & 15)) * LDK + kk]);
            }
#pragma unroll
            for (int mt = 0; mt < 2; ++mt)
#pragma unroll
                for (int nt = 0; nt < 4; ++nt) {
                    acc1[mt][nt] = __builtin_amdgcn_mfma_f32_16x16x32_bf16(
                        af[mt], b1f[nt], acc1[mt][nt], 0, 0, 0);
                    acc3[mt][nt] = __builtin_amdgcn_mfma_f32_16x16x32_bf16(
                        af[mt], b3f[nt], acc3[mt][nt], 0, 0, 0);
                }
        }
        __syncthreads();
    }
    // epilogue: g = silu(h1)*h3 -> bf16
#pragma unroll
    for (int mt = 0; mt < 2; ++mt)
#pragma unroll
        for (int nt = 0; nt < 4; ++nt)
#pragma unroll
            for (int r = 0; r < 4; ++r) {
                int row = m0 + wave * 32 + mt * 16 + (lane >> 4) * 4 + r;
                int col = n0 + nt * 16 + (lane & 15);
                float h1 = acc1[mt][nt][r];
                float h3 = acc3[mt][nt][r];
                float g = (h1 / (1.0f + expf(-h1))) * h3;
                G[(size_t)row * N + col] = f32_to_bf16_raw(g);
            }
}

// gemm2: y = G @ W2^T, out += combine[:,e] * (fractal ? gamma*(xn+y)+x : y)
// G: [4096 x K] bf16.  W2: [1024 x K] fp32.  out: [4096 x 1024] fp32.
__global__ __launch_bounds__(256) void gemm2_kernel(
    const u16* __restrict__ A, const float* __restrict__ B2,
    float* __restrict__ out, const float* __restrict__ combine, int e,
    const float* __restrict__ x, const u16* __restrict__ xn,
    const float* __restrict__ gamma, int K, int is_fractal) {
    __shared__ alignas(16) u16 sA[BM * LDK];
    __shared__ alignas(16) u16 sB[BN * LDK];

    const int tid  = threadIdx.x;
    const int wave = tid >> 6;
    const int lane = tid & 63;
    const int m0 = blockIdx.y * BM;
    const int n0 = blockIdx.x * BN;

    floatx4 acc[2][4];
    floatx4 zero = { 0.f, 0.f, 0.f, 0.f };
#pragma unroll
    for (int mt = 0; mt < 2; ++mt)
#pragma unroll
        for (int nt = 0; nt < 4; ++nt) acc[mt][nt] = zero;

    for (int k0 = 0; k0 < K; k0 += BK) {
#pragma unroll
        for (int it = 0; it < 4; ++it) {
            int idx = it * 2048 + tid * 8;
            int r = idx >> 6, c = idx & 63;
            int4 v = *reinterpret_cast<const int4*>(A + (size_t)(m0 + r) * K + k0 + c);
            *reinterpret_cast<int4*>(&sA[r * LDK + c]) = v;
        }
#pragma unroll
        for (int it = 0; it < 4; ++it) {
            int idx = it * 1024 + tid * 4;
            int r = idx >> 6, c = idx & 63;
            float4 v = *reinterpret_cast<const float4*>(B2 + (size_t)(n0 + r) * K + k0 + c);
            us4 o = { f32_to_bf16_raw(v.x), f32_to_bf16_raw(v.y),
                      f32_to_bf16_raw(v.z), f32_to_bf16_raw(v.w) };
            *reinterpret_cast<us4*>(&sB[r * LDK + c]) = o;
        }
        __syncthreads();
#pragma unroll
        for (int ks = 0; ks < 2; ++ks) {
            const int kk = ks * 32 + (lane >> 4) * 8;
            bf16x8 af[2], bf[4];
#pragma unroll
            for (int mt = 0; mt < 2; ++mt)
                af[mt] = *reinterpret_cast<const bf16x8*>(
                    &sA[(wave * 32 + mt * 16 + (lane & 15)) * LDK + kk]);
#pragma unroll
            for (int nt = 0; nt < 4; ++nt)
                bf[nt] = *reinterpret_cast<const bf16x8*>(
                    &sB[(nt * 16 + (lane & 15)) * LDK + kk]);
#pragma unroll
            for (int mt = 0; mt < 2; ++mt)
#pragma unroll
                for (int nt = 0; nt < 4; ++nt)
                    acc[mt][nt] = __builtin_amdgcn_mfma_f32_16x16x32_bf16(
                        af[mt], bf[nt], acc[mt][nt], 0, 0, 0);
        }
        __syncthreads();
    }
#pragma unroll
    for (int mt = 0; mt < 2; ++mt)
#pragma unroll
        for (int nt = 0; nt < 4; ++nt)
#pragma unroll
            for (int r = 0; r < 4; ++r) {
                int row = m0 + wave * 32 + mt * 16 + (lane >> 4) * 4 + r;
                int col = n0 + nt * 16 + (lane & 15);
                float y = acc[mt][nt][r];
                float coef = combine[(size_t)row * NEXP + e];
                size_t oidx = (size_t)row * DIM + col;
                if (is_fractal) {
                    float xnv = bf16_raw_to_f32(xn[oidx]);
                    float res = gamma[col] * (xnv + y) + x[oidx];
                    out[oidx] += coef * res;
                } else {
                    out[oidx] += coef * y;
                }
            }
}

// ---------------------------------------------------------------- launch
extern "C" void kernel_launch(void* const* d_in, const int* in_sizes, int n_in,
                              void* d_out, int out_size, void* d_ws, size_t ws_size,
                              hipStream_t stream) {
    const float* x          = (const float*)d_in[0];
    const float* router_w   = (const float*)d_in[1];
    const float* frac_rms   = (const float*)d_in[2];
    const float* frac_w1    = (const float*)d_in[3];
    const float* frac_w2    = (const float*)d_in[4];
    const float* frac_w3    = (const float*)d_in[5];
    const float* frac_gamma = (const float*)d_in[6];
    const float* sw_w1      = (const float*)d_in[7];
    const float* sw_w2      = (const float*)d_in[8];
    const float* sw_w3      = (const float*)d_in[9];
    float* out = (float*)d_out;

    // workspace layout
    char* ws = (char*)d_ws;
    float* combine = (float*)ws;                                   // 4096*8*4   = 128 KB
    u16*   x_bf    = (u16*)(ws + (1u << 17));                      // 4096*1024*2 = 8 MB
    u16*   xn_bf   = (u16*)(ws + (1u << 17) + (8u << 20));         // 8 MB
    u16*   g_bf    = (u16*)(ws + (1u << 17) + (16u << 20));        // 4096*4096*2 = 32 MB

    hipMemsetAsync(d_out, 0, (size_t)N_TOK * DIM * sizeof(float), stream);

    cvt_bf16_kernel<<<(N_TOK * DIM) / (4 * 256), 256, 0, stream>>>(x, x_bf);
    router_kernel<<<N_TOK / 4, 256, 0, stream>>>(x, router_w, combine);

    // fractal experts 0..3
    for (int e = 0; e < NFRAC; ++e) {
        rmsnorm_kernel<<<N_TOK, 256, 0, stream>>>(x, frac_rms + (size_t)e * DIM, xn_bf);
        gemm1_dual_kernel<<<dim3(HFRAC / BN, N_TOK / BM), 256, 0, stream>>>(
            xn_bf, frac_w1 + (size_t)e * HFRAC * DIM, frac_w3 + (size_t)e * HFRAC * DIM,
            g_bf, HFRAC, DIM);
        gemm2_kernel<<<dim3(DIM / BN, N_TOK / BM), 256, 0, stream>>>(
            g_bf, frac_w2 + (size_t)e * DIM * HFRAC, out, combine, e,
            x, xn_bf, frac_gamma + (size_t)e * DIM, HFRAC, 1);
    }
    // switch experts 4..7
    for (int j = 0; j < NEXP - NFRAC; ++j) {
        gemm1_dual_kernel<<<dim3(HSW / BN, N_TOK / BM), 256, 0, stream>>>(
            x_bf, sw_w1 + (size_t)j * HSW * DIM, sw_w3 + (size_t)j * HSW * DIM,
            g_bf, HSW, DIM);
        gemm2_kernel<<<dim3(DIM / BN, N_TOK / BM), 256, 0, stream>>>(
            g_bf, sw_w2 + (size_t)j * DIM * HSW, out, combine, NFRAC + j,
            x, nullptr, nullptr, HSW, 0);
    }
}

// Round 2
// 834.144 us; speedup vs baseline: 2.9245x; 2.9245x over previous
//
#include <hip/hip_runtime.h>
#include <stdint.h>

// Problem constants
#define N_TOK 4096
#define DIM   1024
#define HFRAC 2048
#define HSW   4096
#define NEXP  8
#define NFRAC 4
#define TOPK  2
#define TOTAL_ROWS (N_TOK * TOPK)   // 8192, always exact
#define PAD_ROWS   (TOTAL_ROWS + 128)

typedef unsigned short u16;
typedef __bf16 bf16x8 __attribute__((ext_vector_type(8)));
typedef float  floatx4 __attribute__((ext_vector_type(4)));

struct alignas(8)  us4 { u16 v[4]; };
struct alignas(16) us8 { u16 v[8]; };

__device__ __forceinline__ u16 f32_to_bf16_raw(float f) {
    union { float f; uint32_t u; } v; v.f = f;
    uint32_t u = v.u;
    uint32_t r = 0x7FFFu + ((u >> 16) & 1u);   // round-to-nearest-even
    return (u16)((u + r) >> 16);
}
__device__ __forceinline__ float bf16_raw_to_f32(u16 h) {
    union { uint32_t u; float f; } v; v.u = ((uint32_t)h) << 16;
    return v.f;
}

// XOR-swizzled LDS element offset: 64-elem rows, 8-elem (16B) chunks,
// chunk ^= row&7. Writes are bank-balanced; b128 fragment reads are 2-way
// (free). No padding => global_load_lds-compatible layout later if needed.
__device__ __forceinline__ int sw_addr(int row, int chunk) {
    return row * 64 + ((chunk ^ (row & 7)) << 3);
}

// ---------------------------------------------------------------- router
// one wave per token: logits[8] = x . router_w[e] (fp32), softmax, top-2.
// Writes per-token routing (expert ids + renormed coefs) and expert counts.
__global__ __launch_bounds__(256) void router_kernel(
    const float* __restrict__ x, const float* __restrict__ rw,
    int* __restrict__ re, float* __restrict__ rc, int* __restrict__ counts) {
    const int token = blockIdx.x * 4 + (threadIdx.x >> 6);
    const int lane  = threadIdx.x & 63;
    const float* xr = x + (size_t)token * DIM;

    float acc[NEXP];
#pragma unroll
    for (int e = 0; e < NEXP; ++e) acc[e] = 0.0f;
#pragma unroll
    for (int i = 0; i < DIM / 64; ++i) {
        int k = lane + i * 64;
        float xv = xr[k];
#pragma unroll
        for (int e = 0; e < NEXP; ++e) acc[e] += xv * rw[e * DIM + k];
    }
#pragma unroll
    for (int e = 0; e < NEXP; ++e) {
#pragma unroll
        for (int off = 32; off > 0; off >>= 1) acc[e] += __shfl_down(acc[e], off);
    }
    if (lane == 0) {
        float mx = acc[0];
#pragma unroll
        for (int e = 1; e < NEXP; ++e) mx = fmaxf(mx, acc[e]);
        float w[NEXP]; float s = 0.0f;
#pragma unroll
        for (int e = 0; e < NEXP; ++e) { w[e] = expf(acc[e] - mx); s += w[e]; }
        float inv = 1.0f / s;
#pragma unroll
        for (int e = 0; e < NEXP; ++e) w[e] *= inv;
        int i1 = 0;
#pragma unroll
        for (int e = 1; e < NEXP; ++e) if (w[e] > w[i1]) i1 = e;
        int i2 = (i1 == 0) ? 1 : 0;
#pragma unroll
        for (int e = 0; e < NEXP; ++e) if (e != i1 && w[e] > w[i2]) i2 = e;
        float denom = fmaxf(w[i1] + w[i2], 1e-9f);
        re[token]         = i1; rc[token]         = w[i1] / denom;
        re[N_TOK + token] = i2; rc[N_TOK + token] = w[i2] / denom;
        atomicAdd(&counts[i1], 1);
        atomicAdd(&counts[i2], 1);
    }
}

__global__ void offsets_kernel(const int* __restrict__ counts,
                               int* __restrict__ offs) {
    if (threadIdx.x == 0 && blockIdx.x == 0) {
        int a = 0;
#pragma unroll
        for (int e = 0; e < NEXP; ++e) { offs[e] = a; a += counts[e]; }
    }
}

// scatter: assign each (token, slot) a global row
__global__ __launch_bounds__(256) void scatter_kernel(
    const int* __restrict__ re, const float* __restrict__ rc,
    const int* __restrict__ offs, int* __restrict__ cursor,
    int* __restrict__ rowtok, float* __restrict__ co) {
    int token = blockIdx.x * 256 + threadIdx.x;
#pragma unroll
    for (int slot = 0; slot < TOPK; ++slot) {
        int e = re[slot * N_TOK + token];
        int i = atomicAdd(&cursor[e], 1);
        int r = offs[e] + i;
        rowtok[r] = token | (slot << 16);
        co[r]     = rc[slot * N_TOK + token];
    }
}

// gather+norm: A_g[r] = (e<4) ? bf16(rmsnorm(x[token], frac_rms[e])) : bf16(x[token])
__global__ __launch_bounds__(256) void gather_norm_kernel(
    const float* __restrict__ x, const float* __restrict__ frac_rms,
    const int* __restrict__ rowtok, const int* __restrict__ offs,
    u16* __restrict__ Ag) {
    const int r   = blockIdx.x;
    const int tid = threadIdx.x;
    if (r >= TOTAL_ROWS) {                 // zero-fill pad rows
        us4 z = {0, 0, 0, 0};
        reinterpret_cast<us4*>(Ag + (size_t)r * DIM)[tid] = z;
        return;
    }
    int e = 0;
#pragma unroll
    for (int i = 1; i < NEXP; ++i) if (r >= offs[i]) e = i;
    const int token = rowtok[r] & 0xFFFF;
    float4 v = reinterpret_cast<const float4*>(x + (size_t)token * DIM)[tid];
    if (e < NFRAC) {
        float ss = v.x * v.x + v.y * v.y + v.z * v.z + v.w * v.w;
#pragma unroll
        for (int off = 32; off > 0; off >>= 1) ss += __shfl_down(ss, off);
        __shared__ float red[4];
        if ((tid & 63) == 0) red[tid >> 6] = ss;
        __syncthreads();
        float scale = rsqrtf((red[0] + red[1] + red[2] + red[3]) * (1.0f / DIM) + 1e-6f);
        float4 wv = reinterpret_cast<const float4*>(frac_rms + (size_t)e * DIM)[tid];
        v.x *= scale * wv.x; v.y *= scale * wv.y;
        v.z *= scale * wv.z; v.w *= scale * wv.w;
    }
    us4 o = { f32_to_bf16_raw(v.x), f32_to_bf16_raw(v.y),
              f32_to_bf16_raw(v.z), f32_to_bf16_raw(v.w) };
    reinterpret_cast<us4*>(Ag + (size_t)r * DIM)[tid] = o;
}

// ---------------------------------------------------------------- GEMM params
#define BM 128
#define BN 64
#define BK 64

// fused gemm1 (all experts): g = bf16(silu(A@W1^T) * (A@W3^T)) into gbuf
__global__ __launch_bounds__(256) void gemm1_kernel(
    const u16* __restrict__ Ag,
    const float* __restrict__ frac_w1, const float* __restrict__ frac_w3,
    const float* __restrict__ sw_w1,   const float* __restrict__ sw_w3,
    u16* __restrict__ gbuf,
    const int* __restrict__ counts, const int* __restrict__ offs) {
    const int e   = blockIdx.z;
    const int cnt = counts[e];
    const int m0  = blockIdx.y * BM;
    if (m0 >= cnt) return;
    const int Ne = (e < NFRAC) ? HFRAC : HSW;
    const int n0 = blockIdx.x * BN;
    if (n0 >= Ne) return;
    const int rowbase = offs[e];
    const float* W1 = (e < NFRAC) ? frac_w1 + (size_t)e * HFRAC * DIM
                                  : sw_w1 + (size_t)(e - NFRAC) * HSW * DIM;
    const float* W3 = (e < NFRAC) ? frac_w3 + (size_t)e * HFRAC * DIM
                                  : sw_w3 + (size_t)(e - NFRAC) * HSW * DIM;
    const u16* A = Ag + (size_t)(rowbase + m0) * DIM;

    __shared__ u16 sA[BM * BK];
    __shared__ u16 sB1[BN * BK];
    __shared__ u16 sB3[BN * BK];

    const int tid  = threadIdx.x;
    const int wave = tid >> 6;
    const int lane = tid & 63;

    floatx4 acc1[2][4], acc3[2][4];
    floatx4 zero = { 0.f, 0.f, 0.f, 0.f };
#pragma unroll
    for (int mt = 0; mt < 2; ++mt)
#pragma unroll
        for (int nt = 0; nt < 4; ++nt) { acc1[mt][nt] = zero; acc3[mt][nt] = zero; }

    for (int k0 = 0; k0 < DIM; k0 += BK) {
#pragma unroll
        for (int it = 0; it < 4; ++it) {       // A: 128x64 bf16
            int idx = it * 2048 + tid * 8;
            int r = idx >> 6, c = idx & 63;
            int4 v = *reinterpret_cast<const int4*>(A + (size_t)r * DIM + k0 + c);
            *reinterpret_cast<int4*>(&sA[sw_addr(r, c >> 3)]) = v;
        }
#pragma unroll
        for (int it = 0; it < 2; ++it) {       // B1,B3: 64x64 fp32 -> bf16
            int idx = it * 2048 + tid * 8;
            int r = idx >> 6, c = idx & 63;
            size_t go = (size_t)(n0 + r) * DIM + k0 + c;
            float4 a1 = *reinterpret_cast<const float4*>(W1 + go);
            float4 b1 = *reinterpret_cast<const float4*>(W1 + go + 4);
            float4 a3 = *reinterpret_cast<const float4*>(W3 + go);
            float4 b3 = *reinterpret_cast<const float4*>(W3 + go + 4);
            us8 o1 = { f32_to_bf16_raw(a1.x), f32_to_bf16_raw(a1.y),
                       f32_to_bf16_raw(a1.z), f32_to_bf16_raw(a1.w),
                       f32_to_bf16_raw(b1.x), f32_to_bf16_raw(b1.y),
                       f32_to_bf16_raw(b1.z), f32_to_bf16_raw(b1.w) };
            us8 o3 = { f32_to_bf16_raw(a3.x), f32_to_bf16_raw(a3.y),
                       f32_to_bf16_raw(a3.z), f32_to_bf16_raw(a3.w),
                       f32_to_bf16_raw(b3.x), f32_to_bf16_raw(b3.y),
                       f32_to_bf16_raw(b3.z), f32_to_bf16_raw(b3.w) };
            *reinterpret_cast<us8*>(&sB1[sw_addr(r, c >> 3)]) = o1;
            *reinterpret_cast<us8*>(&sB3[sw_addr(r, c >> 3)]) = o3;
        }
        __syncthreads();
#pragma unroll
        for (int ks = 0; ks < 2; ++ks) {
            const int chunk = ks * 4 + (lane >> 4);
            bf16x8 af[2], b1f[4], b3f[4];
#pragma unroll
            for (int mt = 0; mt < 2; ++mt) {
                int ra = wave * 32 + mt * 16 + (lane & 15);
                af[mt] = *reinterpret_cast<const bf16x8*>(&sA[sw_addr(ra, chunk)]);
            }
#pragma unroll
            for (int nt = 0; nt < 4; ++nt) {
                int rb = nt * 16 + (lane & 15);
                b1f[nt] = *reinterpret_cast<const bf16x8*>(&sB1[sw_addr(rb, chunk)]);
                b3f[nt] = *reinterpret_cast<const bf16x8*>(&sB3[sw_addr(rb, chunk)]);
            }
#pragma unroll
            for (int mt = 0; mt < 2; ++mt)
#pragma unroll
                for (int nt = 0; nt < 4; ++nt) {
                    acc1[mt][nt] = __builtin_amdgcn_mfma_f32_16x16x32_bf16(
                        af[mt], b1f[nt], acc1[mt][nt], 0, 0, 0);
                    acc3[mt][nt] = __builtin_amdgcn_mfma_f32_16x16x32_bf16(
                        af[mt], b3f[nt], acc3[mt][nt], 0, 0, 0);
                }
        }
        __syncthreads();
    }
#pragma unroll
    for (int mt = 0; mt < 2; ++mt)
#pragma unroll
        for (int nt = 0; nt < 4; ++nt)
#pragma unroll
            for (int r = 0; r < 4; ++r) {
                int row_local = m0 + wave * 32 + mt * 16 + (lane >> 4) * 4 + r;
                if (row_local >= cnt) continue;
                int col = n0 + nt * 16 + (lane & 15);
                float h1 = acc1[mt][nt][r];
                float h3 = acc3[mt][nt][r];
                float g = (h1 / (1.0f + expf(-h1))) * h3;
                gbuf[(size_t)(rowbase + row_local) * HSW + col] = f32_to_bf16_raw(g);
            }
}

// fused gemm2 (all experts): y = g @ W2^T; write combined contribution into
// ybuf[slot][token] (race-free: each (token,slot) owned by exactly one expert)
__global__ __launch_bounds__(256) void gemm2_kernel(
    const u16* __restrict__ gbuf,
    const float* __restrict__ frac_w2, const float* __restrict__ sw_w2,
    const u16* __restrict__ Ag, const float* __restrict__ x,
    const float* __restrict__ frac_gamma,
    const int* __restrict__ rowtok, const float* __restrict__ co,
    const int* __restrict__ counts, const int* __restrict__ offs,
    float* __restrict__ ybuf) {
    const int e   = blockIdx.z;
    const int cnt = counts[e];
    const int m0  = blockIdx.y * BM;
    if (m0 >= cnt) return;
    const int n0 = blockIdx.x * BN;
    const int Ke = (e < NFRAC) ? HFRAC : HSW;
    const int rowbase = offs[e];
    const float* W2 = (e < NFRAC) ? frac_w2 + (size_t)e * DIM * HFRAC
                                  : sw_w2 + (size_t)(e - NFRAC) * DIM * HSW;
    const u16* A = gbuf + (size_t)(rowbase + m0) * HSW;

    __shared__ u16 sA[BM * BK];
    __shared__ u16 sB[BN * BK];

    const int tid  = threadIdx.x;
    const int wave = tid >> 6;
    const int lane = tid & 63;

    floatx4 acc[2][4];
    floatx4 zero = { 0.f, 0.f, 0.f, 0.f };
#pragma unroll
    for (int mt = 0; mt < 2; ++mt)
#pragma unroll
        for (int nt = 0; nt < 4; ++nt) acc[mt][nt] = zero;

    for (int k0 = 0; k0 < Ke; k0 += BK) {
#pragma unroll
        for (int it = 0; it < 4; ++it) {
            int idx = it * 2048 + tid * 8;
            int r = idx >> 6, c = idx & 63;
            int4 v = *reinterpret_cast<const int4*>(A + (size_t)r * HSW + k0 + c);
            *reinterpret_cast<int4*>(&sA[sw_addr(r, c >> 3)]) = v;
        }
#pragma unroll
        for (int it = 0; it < 2; ++it) {
            int idx = it * 2048 + tid * 8;
            int r = idx >> 6, c = idx & 63;
            size_t go = (size_t)(n0 + r) * Ke + k0 + c;
            float4 a = *reinterpret_cast<const float4*>(W2 + go);
            float4 b = *reinterpret_cast<const float4*>(W2 + go + 4);
            us8 o = { f32_to_bf16_raw(a.x), f32_to_bf16_raw(a.y),
                      f32_to_bf16_raw(a.z), f32_to_bf16_raw(a.w),
                      f32_to_bf16_raw(b.x), f32_to_bf16_raw(b.y),
                      f32_to_bf16_raw(b.z), f32_to_bf16_raw(b.w) };
            *reinterpret_cast<us8*>(&sB[sw_addr(r, c >> 3)]) = o;
        }
        __syncthreads();
#pragma unroll
        for (int ks = 0; ks < 2; ++ks) {
            const int chunk = ks * 4 + (lane >> 4);
            bf16x8 af[2], bf[4];
#pragma unroll
            for (int mt = 0; mt < 2; ++mt) {
                int ra = wave * 32 + mt * 16 + (lane & 15);
                af[mt] = *reinterpret_cast<const bf16x8*>(&sA[sw_addr(ra, chunk)]);
            }
#pragma unroll
            for (int nt = 0; nt < 4; ++nt) {
                int rb = nt * 16 + (lane & 15);
                bf[nt] = *reinterpret_cast<const bf16x8*>(&sB[sw_addr(rb, chunk)]);
            }
#pragma unroll
            for (int mt = 0; mt < 2; ++mt)
#pragma unroll
                for (int nt = 0; nt < 4; ++nt)
                    acc[mt][nt] = __builtin_amdgcn_mfma_f32_16x16x32_bf16(
                        af[mt], bf[nt], acc[mt][nt], 0, 0, 0);
        }
        __syncthreads();
    }
    const float* gamma = frac_gamma + (size_t)e * DIM;
#pragma unroll
    for (int mt = 0; mt < 2; ++mt)
#pragma unroll
        for (int nt = 0; nt < 4; ++nt)
#pragma unroll
            for (int rr = 0; rr < 4; ++rr) {
                int row_local = m0 + wave * 32 + mt * 16 + (lane >> 4) * 4 + rr;
                if (row_local >= cnt) continue;
                int r = rowbase + row_local;
                int col = n0 + nt * 16 + (lane & 15);
                int info  = rowtok[r];
                int token = info & 0xFFFF;
                int slot  = info >> 16;
                float coef = co[r];
                float y = acc[mt][nt][rr];
                float val;
                if (e < NFRAC) {
                    float xn = bf16_raw_to_f32(Ag[(size_t)r * DIM + col]);
                    val = coef * (gamma[col] * (xn + y) + x[(size_t)token * DIM + col]);
                } else {
                    val = coef * y;
                }
                ybuf[(size_t)slot * N_TOK * DIM + (size_t)token * DIM + col] = val;
            }
}

// out = ybuf[0] + ybuf[1]
__global__ __launch_bounds__(256) void combine_kernel(
    const float* __restrict__ ybuf, float* __restrict__ out) {
    size_t i = (size_t)blockIdx.x * 256 + threadIdx.x;   // float4 index
    float4 a = reinterpret_cast<const float4*>(ybuf)[i];
    float4 b = reinterpret_cast<const float4*>(ybuf + (size_t)N_TOK * DIM)[i];
    float4 o = { a.x + b.x, a.y + b.y, a.z + b.z, a.w + b.w };
    reinterpret_cast<float4*>(out)[i] = o;
}

// ---------------------------------------------------------------- launch
extern "C" void kernel_launch(void* const* d_in, const int* in_sizes, int n_in,
                              void* d_out, int out_size, void* d_ws, size_t ws_size,
                              hipStream_t stream) {
    const float* x          = (const float*)d_in[0];
    const float* router_w   = (const float*)d_in[1];
    const float* frac_rms   = (const float*)d_in[2];
    const float* frac_w1    = (const float*)d_in[3];
    const float* frac_w2    = (const float*)d_in[4];
    const float* frac_w3    = (const float*)d_in[5];
    const float* frac_gamma = (const float*)d_in[6];
    const float* sw_w1      = (const float*)d_in[7];
    const float* sw_w2      = (const float*)d_in[8];
    const float* sw_w3      = (const float*)d_in[9];
    float* out = (float*)d_out;

    // workspace layout (~120 MB)
    char* ws = (char*)d_ws;
    int*   counts = (int*)ws;                      // 8 ints
    int*   cursor = (int*)(ws + 32);               // 8 ints
    int*   offs   = (int*)(ws + 64);               // 8 ints
    int*   re     = (int*)(ws + 256);              // 2*4096 ints   (32 KB)
    float* rc     = (float*)(ws + 256 + (32u << 10));  // 32 KB
    int*   rowtok = (int*)(ws + 256 + (64u << 10));    // PAD_ROWS ints (~33 KB)
    float* co     = (float*)(ws + 256 + (112u << 10)); // ~33 KB
    u16*   Ag     = (u16*)(ws + (1u << 18));                       // 8320*1024*2 = 17 MB
    u16*   gbuf   = (u16*)(ws + (size_t)18 * (1u << 20));          // 8320*4096*2 = 68 MB
    float* ybuf   = (float*)(ws + (size_t)88 * (1u << 20));        // 2*4096*1024*4 = 32 MB

    hipMemsetAsync(ws, 0, 256, stream);  // counts + cursor

    router_kernel<<<N_TOK / 4, 256, 0, stream>>>(x, router_w, re, rc, counts);
    offsets_kernel<<<1, 64, 0, stream>>>(counts, offs);
    scatter_kernel<<<N_TOK / 256, 256, 0, stream>>>(re, rc, offs, cursor, rowtok, co);
    gather_norm_kernel<<<PAD_ROWS, 256, 0, stream>>>(x, frac_rms, rowtok, offs, Ag);

    gemm1_kernel<<<dim3(HSW / BN, TOTAL_ROWS / BM, NEXP), 256, 0, stream>>>(
        Ag, frac_w1, frac_w3, sw_w1, sw_w3, gbuf, counts, offs);

    gemm2_kernel<<<dim3(DIM / BN, TOTAL_ROWS / BM, NEXP), 256, 0, stream>>>(
        gbuf, frac_w2, sw_w2, Ag, x, frac_gamma, rowtok, co, counts, offs, ybuf);

    combine_kernel<<<(N_TOK * DIM) / (4 * 256), 256, 0, stream>>>(ybuf, out);
}